// Round 5
// baseline (263.384 us; speedup 1.0000x reference)
//
#include <hip/hip_runtime.h>
#include <hip/hip_bf16.h>
#include <stdint.h>

#define E_EDGES 100000
#define IN_F    256
#define HID     128
#define KNB     16
#define NCHUNK  ((E_EDGES + 63) / 64)   // 1563
#define GEMM_GRID 512

typedef short bf16x8 __attribute__((ext_vector_type(8)));
typedef float f32x4  __attribute__((ext_vector_type(4)));

__device__ __forceinline__ unsigned short f2bf(float f) {
    union { float f; unsigned u; } v; v.f = f;
    unsigned u = v.u;
    u += 0x7fffu + ((u >> 16) & 1u);   // round-to-nearest-even
    return (unsigned short)(u >> 16);
}

// W [256][128] fp32 -> Wtf: bf16 in MFMA B-fragment order.
// Granule d (16 B = 8 bf16): f=d>>6 (f=k0*8+ct), L=d&63 (L=quad*16+l15).
// Granule holds B[k = (k0*4+quad)*8 + j][n = ct*16+l15], j=0..7.
// So gemm staging is a pure stride-1 copy and K-loop B-reads are
// ds_read_b128 at lane*16 (conflict-free).
__global__ void conv_w_kernel(const float* __restrict__ W, unsigned short* __restrict__ Wtf) {
    int d = blockIdx.x * 256 + threadIdx.x;   // 0..4095
    int f = d >> 6, L = d & 63;
    int k0 = f >> 3, ct = f & 7, quad = L >> 4, l15 = L & 15;
    int n  = ct * 16 + l15;
    int kb = (k0 * 4 + quad) * 8;
    const float* wp = W + (size_t)kb * HID + n;
    unsigned short h[8];
    #pragma unroll
    for (int j = 0; j < 8; ++j) h[j] = f2bf(wp[(size_t)j * HID]);
    uint4 o;
    o.x = (unsigned)h[0] | ((unsigned)h[1] << 16);
    o.y = (unsigned)h[2] | ((unsigned)h[3] << 16);
    o.z = (unsigned)h[4] | ((unsigned)h[5] << 16);
    o.w = (unsigned)h[6] | ((unsigned)h[7] << 16);
    *(uint4*)(Wtf + (size_t)d * 8) = o;
}

// T = A @ W + b (A fp32, converted in-reg), stored bf16 [E][128].
// Grid = 512 blocks; each block stages Wt->LDS ONCE (stride-1 copy, conflict-free),
// then loops over ~3 chunks of 64 rows with NO further barriers — LDS is read-only,
// so waves drift and overlap each other's A-load latency.
__launch_bounds__(256, 2)
__global__ void gemm_t_kernel(const float* __restrict__ A,
                              const unsigned short* __restrict__ Wtf,
                              const float* __restrict__ bias,
                              unsigned short* __restrict__ T) {
    __shared__ unsigned short Bs[32768];   // 64 KB, fragment order
    const int tid  = threadIdx.x;
    const int wave = tid >> 6;
    const int lane = tid & 63;
    const int l15  = lane & 15;
    const int quad = lane >> 4;

    // Stage Wt -> LDS: pure stride-1 uint4 copy (coalesced read, conflict-free write).
    #pragma unroll
    for (int it = 0; it < 16; ++it) {
        int d = it * 256 + tid;
        *(uint4*)(Bs + (size_t)d * 8) = *(const uint4*)(Wtf + (size_t)d * 8);
    }

    // Per-lane bias for its 8 columns (col = ct*16 + l15).
    float bv[8];
    #pragma unroll
    for (int ct = 0; ct < 8; ++ct) bv[ct] = bias[ct * 16 + l15];

    __syncthreads();

    for (int c = blockIdx.x; c < NCHUNK; c += GEMM_GRID) {
        const int rowbase = c * 64 + wave * 16;
        int arow = rowbase + l15;
        if (arow >= E_EDGES) arow = E_EDGES - 1;   // clamp; stores guarded below

        // Full-K fp32 A prefetch: 16 float4 per lane.
        const float* ap = A + (size_t)arow * IN_F + quad * 8;
        float4 af32[16];
        #pragma unroll
        for (int k0 = 0; k0 < 8; ++k0) {
            af32[2 * k0]     = *(const float4*)(ap + k0 * 32);
            af32[2 * k0 + 1] = *(const float4*)(ap + k0 * 32 + 4);
        }

        // Convert to bf16 A-fragments.
        bf16x8 apre[8];
        #pragma unroll
        for (int k0 = 0; k0 < 8; ++k0) {
            float4 lo = af32[2 * k0], hi = af32[2 * k0 + 1];
            bf16x8 f;
            f[0] = (short)f2bf(lo.x); f[1] = (short)f2bf(lo.y);
            f[2] = (short)f2bf(lo.z); f[3] = (short)f2bf(lo.w);
            f[4] = (short)f2bf(hi.x); f[5] = (short)f2bf(hi.y);
            f[6] = (short)f2bf(hi.z); f[7] = (short)f2bf(hi.w);
            apre[k0] = f;
        }

        f32x4 acc[8] = {};
        #pragma unroll
        for (int k0 = 0; k0 < 8; ++k0) {
            #pragma unroll
            for (int ct = 0; ct < 8; ++ct) {
                bf16x8 bf = *(const bf16x8*)(Bs + ((size_t)((k0 * 8 + ct) * 64 + lane)) * 8);
                acc[ct] = __builtin_amdgcn_mfma_f32_16x16x32_bf16(apre[k0], bf, acc[ct], 0, 0, 0);
            }
        }

        // Epilogue: +bias, bf16 store. C/D layout: col = l15, row = quad*4 + reg.
        #pragma unroll
        for (int ct = 0; ct < 8; ++ct) {
            const int col = ct * 16 + l15;
            #pragma unroll
            for (int i = 0; i < 4; ++i) {
                const int row = rowbase + quad * 4 + i;
                if (row < E_EDGES)
                    T[(size_t)row * HID + col] = f2bf(acc[ct][i] + bv[ct]);
            }
        }
    }
}

// out[i] = t[i] + sum_k t[nbr[i][k]]  (fp32 accumulate from bf16 t)
// Block = 256 thr = 16 edges; 16 lanes/edge, 8 feats/lane via uint4 (8 bf16).
// All 17 row-loads issue as one group (sched_barrier pins them) -> max MLP.
__launch_bounds__(256)
__global__ void gather_sum_kernel(const unsigned short* __restrict__ T,
                                  const int* __restrict__ nbr,
                                  float* __restrict__ out) {
    __shared__ int sidx[256];
    const int tid   = threadIdx.x;
    const int edge0 = blockIdx.x * 16;
    sidx[tid] = nbr[(size_t)edge0 * KNB + tid];   // 16 edges x 16 nbrs
    __syncthreads();

    const int el   = tid >> 4;        // local edge 0..15
    const int lane = tid & 15;        // feature group: feats [lane*8, lane*8+8)
    const int edge = edge0 + el;

    const unsigned short* tb = T + (size_t)lane * 8;
    uint4 v[17];
    v[0] = *(const uint4*)(tb + (size_t)edge * HID);
    #pragma unroll
    for (int k = 0; k < KNB; ++k)
        v[k + 1] = *(const uint4*)(tb + (size_t)sidx[el * KNB + k] * HID);
    __builtin_amdgcn_sched_barrier(0);   // keep all 17 loads in flight together

    float acc[8] = {};
    #pragma unroll
    for (int k = 0; k < 17; ++k) {
        unsigned w[4] = { v[k].x, v[k].y, v[k].z, v[k].w };
        union { unsigned u; float f; } c;
        #pragma unroll
        for (int j = 0; j < 4; ++j) {
            c.u = w[j] << 16;          acc[2 * j]     += c.f;
            c.u = w[j] & 0xffff0000u;  acc[2 * j + 1] += c.f;
        }
    }

    float* op = out + (size_t)edge * HID + lane * 8;
    float4 o0 = { acc[0], acc[1], acc[2], acc[3] };
    float4 o1 = { acc[4], acc[5], acc[6], acc[7] };
    *(float4*)op       = o0;
    *(float4*)(op + 4) = o1;
}

extern "C" void kernel_launch(void* const* d_in, const int* in_sizes, int n_in,
                              void* d_out, int out_size, void* d_ws, size_t ws_size,
                              hipStream_t stream) {
    const float* edge_feats = (const float*)d_in[0];   // [E, 256] fp32
    const int*   neighbors  = (const int*)d_in[1];     // [E, 16] int32
    const float* W          = (const float*)d_in[2];   // [256, 128] fp32
    const float* b          = (const float*)d_in[3];   // [128] fp32
    float*       out        = (float*)d_out;           // [E, 128] fp32

    unsigned short* Wtf = (unsigned short*)d_ws;                      // 64 KB, fragment order
    unsigned short* T   = (unsigned short*)d_ws + (size_t)IN_F * HID; // 25.6 MB

    conv_w_kernel<<<16, 256, 0, stream>>>(W, Wtf);
    gemm_t_kernel<<<GEMM_GRID, 256, 0, stream>>>(edge_feats, Wtf, b, T);
    gather_sum_kernel<<<E_EDGES / 16, 256, 0, stream>>>(T, neighbors, out);
}

// Round 6
// 231.721 us; speedup vs baseline: 1.1366x; 1.1366x over previous
//
#include <hip/hip_runtime.h>
#include <hip/hip_bf16.h>
#include <stdint.h>

#define E_EDGES 100000
#define IN_F    256
#define HID     128
#define KNB     16
#define NCHUNK  ((E_EDGES + 63) / 64)   // 1563
#define GEMM_GRID 512

typedef short bf16x8 __attribute__((ext_vector_type(8)));
typedef float f32x4  __attribute__((ext_vector_type(4)));

__device__ __forceinline__ unsigned short f2bf(float f) {
    union { float f; unsigned u; } v; v.f = f;
    unsigned u = v.u;
    u += 0x7fffu + ((u >> 16) & 1u);   // round-to-nearest-even
    return (unsigned short)(u >> 16);
}

// W [256][128] fp32 -> Wtf: bf16 in MFMA B-fragment order.
// Granule d (16 B = 8 bf16): f=d>>6 (f=k0*8+ct), L=d&63 (L=quad*16+l15).
// Granule holds W^T[n = ct*16+l15][k = (k0*4+quad)*8 + j], j=0..7.
__global__ void conv_w_kernel(const float* __restrict__ W, unsigned short* __restrict__ Wtf) {
    int d = blockIdx.x * 256 + threadIdx.x;   // 0..4095
    int f = d >> 6, L = d & 63;
    int k0 = f >> 3, ct = f & 7, quad = L >> 4, l15 = L & 15;
    int n  = ct * 16 + l15;
    int kb = (k0 * 4 + quad) * 8;
    const float* wp = W + (size_t)kb * HID + n;
    unsigned short h[8];
    #pragma unroll
    for (int j = 0; j < 8; ++j) h[j] = f2bf(wp[(size_t)j * HID]);
    uint4 o;
    o.x = (unsigned)h[0] | ((unsigned)h[1] << 16);
    o.y = (unsigned)h[2] | ((unsigned)h[3] << 16);
    o.z = (unsigned)h[4] | ((unsigned)h[5] << 16);
    o.w = (unsigned)h[6] | ((unsigned)h[7] << 16);
    *(uint4*)(Wtf + (size_t)d * 8) = o;
}

// T = A @ W + b (A fp32, converted in-reg), stored bf16 [E][128].
// Grid = 512; each block stages Wt->LDS once (stride-1, conflict-free), then
// grid-strides over 64-row chunks. A is DOUBLE-BUFFERED across chunks: next
// chunk's 16 float4 loads issue before the MFMA loop (sched_barrier-pinned)
// and drain across MFMA+epilogue — K-loop reads LDS only (lgkmcnt), so the
// A-prefetch vmcnt queue never blocks it. MFMA operands are SWAPPED
// (mfma(b,a)) so each lane owns one T-row with 4 consecutive cols per ct ->
// packed 8B stores, no partial-line write bloat.
__launch_bounds__(256, 2)
__global__ void gemm_t_kernel(const float* __restrict__ A,
                              const unsigned short* __restrict__ Wtf,
                              const float* __restrict__ bias,
                              unsigned short* __restrict__ T) {
    __shared__ unsigned short Bs[32768];   // 64 KB, fragment order
    const int tid  = threadIdx.x;
    const int wave = tid >> 6;
    const int lane = tid & 63;
    const int l15  = lane & 15;
    const int quad = lane >> 4;

    // Chunk-0 A prefetch BEFORE staging: overlaps the staging + barrier drain.
    int c = blockIdx.x;
    int arow = c * 64 + wave * 16 + l15;
    if (arow >= E_EDGES) arow = E_EDGES - 1;
    const float* ap = A + (size_t)arow * IN_F + quad * 8;
    float4 af32[16];
    #pragma unroll
    for (int k0 = 0; k0 < 8; ++k0) {
        af32[2 * k0]     = *(const float4*)(ap + k0 * 32);
        af32[2 * k0 + 1] = *(const float4*)(ap + k0 * 32 + 4);
    }

    // Stage Wtf -> LDS: pure stride-1 uint4 copy (coalesced, conflict-free).
    #pragma unroll
    for (int it = 0; it < 16; ++it) {
        int d = it * 256 + tid;
        *(uint4*)(Bs + (size_t)d * 8) = *(const uint4*)(Wtf + (size_t)d * 8);
    }

    // Per-lane bias for its 4 cols per ct: col = ct*16 + quad*4 + i.
    float4 bv4[8];
    #pragma unroll
    for (int ct = 0; ct < 8; ++ct)
        bv4[ct] = *(const float4*)(bias + ct * 16 + quad * 4);

    __syncthreads();

    for (; c < NCHUNK; c += GEMM_GRID) {
        // Convert current A to bf16 fragments (waits on the in-flight loads).
        bf16x8 apre[8];
        #pragma unroll
        for (int k0 = 0; k0 < 8; ++k0) {
            float4 lo = af32[2 * k0], hi = af32[2 * k0 + 1];
            bf16x8 f;
            f[0] = (short)f2bf(lo.x); f[1] = (short)f2bf(lo.y);
            f[2] = (short)f2bf(lo.z); f[3] = (short)f2bf(lo.w);
            f[4] = (short)f2bf(hi.x); f[5] = (short)f2bf(hi.y);
            f[6] = (short)f2bf(hi.z); f[7] = (short)f2bf(hi.w);
            apre[k0] = f;
        }

        // Issue NEXT chunk's A loads now; they drain across MFMA + epilogue.
        {
            int cn = c + GEMM_GRID;
            int arow2 = cn * 64 + wave * 16 + l15;
            if (arow2 >= E_EDGES) arow2 = E_EDGES - 1;   // harmless redundant loads on last iter
            const float* ap2 = A + (size_t)arow2 * IN_F + quad * 8;
            #pragma unroll
            for (int k0 = 0; k0 < 8; ++k0) {
                af32[2 * k0]     = *(const float4*)(ap2 + k0 * 32);
                af32[2 * k0 + 1] = *(const float4*)(ap2 + k0 * 32 + 4);
            }
        }
        __builtin_amdgcn_sched_barrier(0);   // pin the prefetch above the MFMA loop

        f32x4 acc[8] = {};
        #pragma unroll
        for (int k0 = 0; k0 < 8; ++k0) {
            #pragma unroll
            for (int ct = 0; ct < 8; ++ct) {
                bf16x8 bf = *(const bf16x8*)(Bs + ((size_t)((k0 * 8 + ct) * 64 + lane)) * 8);
                // swapped: D = W_tile^T * A_tile^T = T-tile transposed
                acc[ct] = __builtin_amdgcn_mfma_f32_16x16x32_bf16(bf, apre[k0], acc[ct], 0, 0, 0);
            }
        }

        // Epilogue: lane owns T-row (c*64 + wave*16 + l15); per ct, 4 consecutive
        // cols ct*16 + quad*4 + i. Packed 8 B stores.
        const int row = c * 64 + wave * 16 + l15;
        if (row < E_EDGES) {
            unsigned short* tp = T + (size_t)row * HID + quad * 4;
            #pragma unroll
            for (int ct = 0; ct < 8; ++ct) {
                unsigned short h0 = f2bf(acc[ct][0] + bv4[ct].x);
                unsigned short h1 = f2bf(acc[ct][1] + bv4[ct].y);
                unsigned short h2 = f2bf(acc[ct][2] + bv4[ct].z);
                unsigned short h3 = f2bf(acc[ct][3] + bv4[ct].w);
                uint2 o;
                o.x = (unsigned)h0 | ((unsigned)h1 << 16);
                o.y = (unsigned)h2 | ((unsigned)h3 << 16);
                *(uint2*)(tp + ct * 16) = o;
            }
        }
    }
}

// out[i] = t[i] + sum_k t[nbr[i][k]]  (fp32 accumulate from bf16 t)
// Block = 256 thr = 16 edges; 16 lanes/edge, 8 feats/lane via uint4 (8 bf16).
// All 17 row-loads issue as one group (sched_barrier pins them) -> max MLP.
__launch_bounds__(256)
__global__ void gather_sum_kernel(const unsigned short* __restrict__ T,
                                  const int* __restrict__ nbr,
                                  float* __restrict__ out) {
    __shared__ int sidx[256];
    const int tid   = threadIdx.x;
    const int edge0 = blockIdx.x * 16;
    sidx[tid] = nbr[(size_t)edge0 * KNB + tid];   // 16 edges x 16 nbrs
    __syncthreads();

    const int el   = tid >> 4;        // local edge 0..15
    const int lane = tid & 15;        // feature group: feats [lane*8, lane*8+8)
    const int edge = edge0 + el;

    const unsigned short* tb = T + (size_t)lane * 8;
    uint4 v[17];
    v[0] = *(const uint4*)(tb + (size_t)edge * HID);
    #pragma unroll
    for (int k = 0; k < KNB; ++k)
        v[k + 1] = *(const uint4*)(tb + (size_t)sidx[el * KNB + k] * HID);
    __builtin_amdgcn_sched_barrier(0);   // keep all 17 loads in flight together

    float acc[8] = {};
    #pragma unroll
    for (int k = 0; k < 17; ++k) {
        unsigned w[4] = { v[k].x, v[k].y, v[k].z, v[k].w };
        union { unsigned u; float f; } c;
        #pragma unroll
        for (int j = 0; j < 4; ++j) {
            c.u = w[j] << 16;          acc[2 * j]     += c.f;
            c.u = w[j] & 0xffff0000u;  acc[2 * j + 1] += c.f;
        }
    }

    float* op = out + (size_t)edge * HID + lane * 8;
    float4 o0 = { acc[0], acc[1], acc[2], acc[3] };
    float4 o1 = { acc[4], acc[5], acc[6], acc[7] };
    *(float4*)op       = o0;
    *(float4*)(op + 4) = o1;
}

extern "C" void kernel_launch(void* const* d_in, const int* in_sizes, int n_in,
                              void* d_out, int out_size, void* d_ws, size_t ws_size,
                              hipStream_t stream) {
    const float* edge_feats = (const float*)d_in[0];   // [E, 256] fp32
    const int*   neighbors  = (const int*)d_in[1];     // [E, 16] int32
    const float* W          = (const float*)d_in[2];   // [256, 128] fp32
    const float* b          = (const float*)d_in[3];   // [128] fp32
    float*       out        = (float*)d_out;           // [E, 128] fp32

    unsigned short* Wtf = (unsigned short*)d_ws;                      // 64 KB, fragment order
    unsigned short* T   = (unsigned short*)d_ws + (size_t)IN_F * HID; // 25.6 MB

    conv_w_kernel<<<16, 256, 0, stream>>>(W, Wtf);
    gemm_t_kernel<<<GEMM_GRID, 256, 0, stream>>>(edge_feats, Wtf, b, T);
    gather_sum_kernel<<<E_EDGES / 16, 256, 0, stream>>>(T, neighbors, out);
}